// Round 12
// baseline (355.842 us; speedup 1.0000x reference)
//
#include <hip/hip_runtime.h>
#include <hip/hip_bf16.h>

#define N_NODES 100000
#define N_EDGES 600000
#define N_REL   3
#define D_INF   256
#define D_OUTF  128

#define SCAN_TOTAL (3 * N_NODES)                 // 300000
#define SCAN_ELEMS 1024                          // elems per block
#define SCAN_NBLK  ((SCAN_TOTAL + SCAN_ELEMS - 1) / SCAN_ELEMS)  // 293

#define NPROJ_BLOCKS (((N_NODES + 63) / 64) * 2)        // 3126
#define NSCAT_BLOCKS ((3 * N_EDGES + 255) / 256)        // 7032
#define NTOT_BLOCKS  (NPROJ_BLOCKS + NSCAT_BLOCKS)      // 10158

typedef __attribute__((ext_vector_type(8))) short          bf16x8;
typedef __attribute__((ext_vector_type(8))) unsigned short ushort8;
typedef __attribute__((ext_vector_type(4))) float          f32x4;

// x-tile LDS row stride (bf16 elems): 144B rows, 16B aligned, ~2-way bank
#define LPAD 72
// phase-2 lbf staging stride (reuses xs region): 272B rows
#define LTS  136

__device__ __forceinline__ unsigned short bf16_rne(float v) {
    unsigned int b = __float_as_uint(v);
    b += 0x7FFFu + ((b >> 16) & 1u);
    return (unsigned short)(b >> 16);
}

// ---------------------------------------------------------------------------
// K0: W [256][128] f32 -> wt packed in MFMA B-fragment order.
// frag(w,plane,kb,kk,cf) = 512 bf16 = lane-major 16B/lane; element (lane,j) =
// W[k = kb*64+kk*32+(lane>>4)*8+j][col = cf*16+(lane&15)], plane 0=hi 1=lo.
// ---------------------------------------------------------------------------
__global__ __launch_bounds__(128) void wt_prep(
    const float* __restrict__ Wl, const float* __restrict__ Wr,
    unsigned short* __restrict__ wt)
{
    const int k = blockIdx.x;      // 0..255
    const int w = blockIdx.y;      // 0,1
    const int n = threadIdx.x;     // 0..127 (col)
    const float v = (w ? Wr : Wl)[(size_t)k * D_OUTF + n];
    const unsigned short h = bf16_rne(v);
    const float fhi = __uint_as_float(((unsigned int)h) << 16);
    const unsigned short g = bf16_rne(v - fhi);

    const int kb   = k >> 6;
    const int kk   = (k >> 5) & 1;
    const int lgrp = (k >> 3) & 3;
    const int j    = k & 7;
    const int cf   = n >> 4;
    const int lane = lgrp * 16 + (n & 15);
    const size_t fh = ((((size_t)(w * 2 + 0) * 4 + kb) * 2 + kk) * 8 + cf) * 512 + lane * 8 + j;
    const size_t fl = ((((size_t)(w * 2 + 1) * 4 + kb) * 2 + kk) * 8 + cf) * 512 + lane * 8 + j;
    wt[fh] = h;
    wt[fl] = g;
}

// ---------------------------------------------------------------------------
// K1 (FUSED): proj GEMM (split-bf16 MFMA; W from packed global frags, no W
// LDS; al/ar via in-register f32 dot + shfl reduce) ∥ CSR scatter.
// LDS = 18 KB, launch_bounds(256,4) -> ~4 blocks/CU so scatter keeps MLP.
// ---------------------------------------------------------------------------
__global__ __launch_bounds__(256, 4) void proj_scatter(
    const float* __restrict__ x, const unsigned short* __restrict__ wt,
    const float* __restrict__ bl, const float* __restrict__ br,
    const float* __restrict__ attn,
    float* __restrict__ rbuf,
    float* __restrict__ al,   float* __restrict__ ar,
    unsigned short* __restrict__ lbf,
    const int* __restrict__ ei, int* __restrict__ cursor,
    int* __restrict__ colall)
{
    __shared__ unsigned short smem[2 * 64 * LPAD];   // 18432 B

    const int bid = blockIdx.x;
    const unsigned int pb = (unsigned int)(((unsigned long long)bid * NPROJ_BLOCKS) / NTOT_BLOCKS);
    const unsigned int pa = (unsigned int)(((unsigned long long)(bid + 1) * NPROJ_BLOCKS) / NTOT_BLOCKS);

    if (pa == pb) {
        // ================= scatter block =================
        const int sb = bid - (int)pb;
        const int ge = sb * 256 + threadIdx.x;
        if (ge < 3 * N_EDGES) {
            const int rr = (ge >= 2 * N_EDGES) ? 2 : ((ge >= N_EDGES) ? 1 : 0);
            const int e  = ge - rr * N_EDGES;
            const int src = ei[(size_t)rr * 2 * N_EDGES + e];
            const int dst = ei[(size_t)rr * 2 * N_EDGES + N_EDGES + e];
            const int pos = atomicAdd(&cursor[rr * N_NODES + dst], 1);
            colall[pos] = src;
        }
        return;
    }

    // ================= proj block #pb =================
    const int tid  = threadIdx.x;
    const int nb   = (int)(pb >> 1) * 64;
    const int w    = (int)(pb & 1);
    const float* bias = w ? br : bl;

    const int lane = tid & 63;
    const int wv   = tid >> 6;      // wave 0..3
    const int rowf = lane & 15;
    const int kgrp = lane >> 4;     // 0..3

    f32x4 acc[8];
#pragma unroll
    for (int cf = 0; cf < 8; ++cf) acc[cf] = (f32x4){0.f, 0.f, 0.f, 0.f};

    float bv[8];
#pragma unroll
    for (int cf = 0; cf < 8; ++cf) bv[cf] = bias[cf * 16 + rowf];

    for (int kb4 = 0; kb4 < 4; ++kb4) {
        __syncthreads();
        // ---- stage x tile: thread t -> row t>>2, 16 k's at (t&3)*16
        {
            const int r   = tid >> 2;
            const int seg = tid & 3;
            int rowg = nb + r; if (rowg >= N_NODES) rowg = N_NODES - 1;
            const float* src = x + (size_t)rowg * D_INF + kb4 * 64 + seg * 16;
#pragma unroll
            for (int q2 = 0; q2 < 2; ++q2) {
                const float4 v0 = *reinterpret_cast<const float4*>(src + q2 * 8);
                const float4 v1 = *reinterpret_cast<const float4*>(src + q2 * 8 + 4);
                const float vv[8] = {v0.x, v0.y, v0.z, v0.w, v1.x, v1.y, v1.z, v1.w};
                ushort8 hv, gv;
#pragma unroll
                for (int q = 0; q < 8; ++q) {
                    const unsigned short h = bf16_rne(vv[q]);
                    hv[q] = h;
                    const float fhi = __uint_as_float(((unsigned int)h) << 16);
                    gv[q] = bf16_rne(vv[q] - fhi);
                }
                *reinterpret_cast<ushort8*>(&smem[0 * 64 * LPAD + r * LPAD + seg * 16 + q2 * 8]) = hv;
                *reinterpret_cast<ushort8*>(&smem[1 * 64 * LPAD + r * LPAD + seg * 16 + q2 * 8]) = gv;
            }
        }
        __syncthreads();

        // ---- MFMA; B-frags loaded directly from packed wt (coalesced, L1/L2)
#pragma unroll
        for (int kk = 0; kk < 2; ++kk) {
            const int ko = kk * 32 + kgrp * 8;
            const bf16x8 ahi = *reinterpret_cast<const bf16x8*>(&smem[0 * 64 * LPAD + (wv * 16 + rowf) * LPAD + ko]);
            const bf16x8 alo = *reinterpret_cast<const bf16x8*>(&smem[1 * 64 * LPAD + (wv * 16 + rowf) * LPAD + ko]);
#pragma unroll
            for (int cf = 0; cf < 8; ++cf) {
                const bf16x8 bhi = *reinterpret_cast<const bf16x8*>(
                    wt + ((((size_t)(w * 2 + 0) * 4 + kb4) * 2 + kk) * 8 + cf) * 512 + lane * 8);
                const bf16x8 blo = *reinterpret_cast<const bf16x8*>(
                    wt + ((((size_t)(w * 2 + 1) * 4 + kb4) * 2 + kk) * 8 + cf) * 512 + lane * 8);
                acc[cf] = __builtin_amdgcn_mfma_f32_16x16x32_bf16(ahi, bhi, acc[cf], 0, 0, 0);
                acc[cf] = __builtin_amdgcn_mfma_f32_16x16x32_bf16(ahi, blo, acc[cf], 0, 0, 0);
                acc[cf] = __builtin_amdgcn_mfma_f32_16x16x32_bf16(alo, bhi, acc[cf], 0, 0, 0);
            }
        }
    }
    __syncthreads();   // xs reads done; safe to reuse smem in phase 2

    // ==== phase 2: relu + outputs ====
    float o_[8][4];
#pragma unroll
    for (int cf = 0; cf < 8; ++cf)
#pragma unroll
        for (int j = 0; j < 4; ++j)
            o_[cf][j] = fmaxf(acc[cf][j] + bv[cf], 0.f);

    if (w == 1) {
#pragma unroll
        for (int cf = 0; cf < 8; ++cf)
#pragma unroll
            for (int j = 0; j < 4; ++j) {
                const int node = nb + wv * 16 + kgrp * 4 + j;
                if (node < N_NODES)
                    rbuf[(size_t)node * D_OUTF + cf * 16 + rowf] = o_[cf][j];
            }
    }

    // al/ar: f32 dot with attn band + 16-lane shfl reduce (over rowf)
    {
        const int woff = w ? 32 : 0;
        float* tab = w ? ar : al;
#pragma unroll
        for (int rr = 0; rr < 3; ++rr) {
            float pr[4][4];
#pragma unroll
            for (int hh = 0; hh < 4; ++hh) {
                const float A0 = attn[rr * 256 + hh * 64 + woff + rowf];
                const float A1 = attn[rr * 256 + hh * 64 + woff + 16 + rowf];
#pragma unroll
                for (int j = 0; j < 4; ++j)
                    pr[hh][j] = fmaf(o_[2 * hh][j], A0, o_[2 * hh + 1][j] * A1);
            }
#pragma unroll
            for (int hh = 0; hh < 4; ++hh)
#pragma unroll
                for (int j = 0; j < 4; ++j) {
#pragma unroll
                    for (int m = 8; m >= 1; m >>= 1)
                        pr[hh][j] += __shfl_xor(pr[hh][j], m);
                }
            if ((rowf >> 2) == rr) {
#pragma unroll
                for (int j = 0; j < 4; ++j) {
                    float v = pr[0][j];
#pragma unroll
                    for (int hh = 1; hh < 4; ++hh)
                        if ((rowf & 3) == hh) v = pr[hh][j];
                    const int node = nb + wv * 16 + kgrp * 4 + j;
                    if (node < N_NODES) tab[(size_t)node * 12 + rowf] = v;
                }
            }
        }
    }

    // lbf (bf16 l copy) via smem staging, coalesced  (w==0 only)
    if (w == 0) {
#pragma unroll
        for (int cf = 0; cf < 8; ++cf)
#pragma unroll
            for (int j = 0; j < 4; ++j)
                smem[(wv * 16 + kgrp * 4 + j) * LTS + cf * 16 + rowf] = bf16_rne(o_[cf][j]);
        __syncthreads();
#pragma unroll
        for (int q = 0; q < 4; ++q) {
            const int idx = tid + q * 256;     // 0..1023 chunks of 8 us
            const int r   = idx >> 4;
            const int c8  = (idx & 15) * 8;
            const int node = nb + r;
            if (node < N_NODES)
                *reinterpret_cast<ushort8*>(&lbf[(size_t)node * D_OUTF + c8]) =
                    *reinterpret_cast<ushort8*>(&smem[r * LTS + c8]);
        }
    }
}

// ---------------------------------------------------------------------------
// K3: degree histogram (by dst)
// ---------------------------------------------------------------------------
__global__ __launch_bounds__(256) void hist_kernel(const int* __restrict__ ei,
                                                   int* __restrict__ deg)
{
    const int rr = blockIdx.y;
    const int e  = blockIdx.x * 256 + threadIdx.x;
    if (e < N_EDGES) {
        const int dst = ei[(size_t)rr * 2 * N_EDGES + N_EDGES + e];
        atomicAdd(&deg[rr * N_NODES + dst], 1);
    }
}

// ---------------------------------------------------------------------------
// K4a: per-block reduce (1024 elems/block, 256 thr x 4)
// ---------------------------------------------------------------------------
__global__ __launch_bounds__(256) void scan_reduce(const int* __restrict__ deg,
                                                   int* __restrict__ blksum)
{
    __shared__ int ws[4];
    const int tid  = threadIdx.x;
    const int lane = tid & 63;
    const int wid  = tid >> 6;
    const int idx  = blockIdx.x * SCAN_ELEMS + tid * 4;
    int t = 0;
#pragma unroll
    for (int j = 0; j < 4; ++j)
        if (idx + j < SCAN_TOTAL) t += deg[idx + j];
#pragma unroll
    for (int off = 32; off >= 1; off >>= 1) t += __shfl_xor(t, off);
    if (lane == 0) ws[wid] = t;
    __syncthreads();
    if (tid == 0) blksum[blockIdx.x] = ws[0] + ws[1] + ws[2] + ws[3];
}

// ---------------------------------------------------------------------------
// K4b: single-block exclusive scan of the 293 block sums (512 threads)
// ---------------------------------------------------------------------------
__global__ __launch_bounds__(512) void scan_mid(int* __restrict__ blksum)
{
    __shared__ int sh[512];
    const int tid = threadIdx.x;
    const int v = (tid < SCAN_NBLK) ? blksum[tid] : 0;
    sh[tid] = v;
    __syncthreads();
#pragma unroll
    for (int off = 1; off < 512; off <<= 1) {
        const int u = (tid >= off) ? sh[tid - off] : 0;
        __syncthreads();
        sh[tid] += u;
        __syncthreads();
    }
    if (tid < SCAN_NBLK) blksum[tid] = sh[tid] - v;   // exclusive
}

// ---------------------------------------------------------------------------
// K4c: per-block scan + block offset -> rowst, cursor
// ---------------------------------------------------------------------------
__global__ __launch_bounds__(256) void scan_final(const int* __restrict__ deg,
    const int* __restrict__ blkoff, int* __restrict__ rowst,
    int* __restrict__ cursor)
{
    __shared__ int wsum[4];
    __shared__ int wexcl[4];
    const int tid  = threadIdx.x;
    const int lane = tid & 63;
    const int wid  = tid >> 6;
    const int idx  = blockIdx.x * SCAN_ELEMS + tid * 4;

    const int v0 = (idx + 0 < SCAN_TOTAL) ? deg[idx + 0] : 0;
    const int v1 = (idx + 1 < SCAN_TOTAL) ? deg[idx + 1] : 0;
    const int v2 = (idx + 2 < SCAN_TOTAL) ? deg[idx + 2] : 0;
    const int v3 = (idx + 3 < SCAN_TOTAL) ? deg[idx + 3] : 0;
    const int tsum = v0 + v1 + v2 + v3;
    int inc = tsum;
#pragma unroll
    for (int off = 1; off < 64; off <<= 1) {
        const int u = __shfl_up(inc, off);
        if (lane >= off) inc += u;
    }
    if (lane == 63) wsum[wid] = inc;
    __syncthreads();
    if (tid == 0) {
        int s = 0;
#pragma unroll
        for (int i = 0; i < 4; ++i) { const int t2 = wsum[i]; wexcl[i] = s; s += t2; }
    }
    __syncthreads();
    const int start = blkoff[blockIdx.x] + wexcl[wid] + (inc - tsum);
    if (idx + 0 < SCAN_TOTAL) { rowst[idx + 0] = start; cursor[idx + 0] = start; }
    const int s1 = start + v0;
    if (idx + 1 < SCAN_TOTAL) { rowst[idx + 1] = s1; cursor[idx + 1] = s1; }
    const int s2 = s1 + v1;
    if (idx + 2 < SCAN_TOTAL) { rowst[idx + 2] = s2; cursor[idx + 2] = s2; }
    const int s3 = s2 + v2;
    if (idx + 3 < SCAN_TOTAL) { rowst[idx + 3] = s3; cursor[idx + 3] = s3; }
}

// ---------------------------------------------------------------------------
// K6: aggregation v4.  2 nodes per wave (32 lanes each, 4 ch/lane); the 3
// relations' edge loops run FUSED in lockstep: phase A for all 3 upfront,
// one combined phase-B loop -> 3 independent gathers in flight per iter.
// ---------------------------------------------------------------------------
__global__ __launch_bounds__(256) void aggregate_kernel(
    const unsigned int* __restrict__ lbf32, const float* __restrict__ rbuf,
    const float* __restrict__ al,   const float* __restrict__ ar,
    const int* __restrict__ rowst,  const int* __restrict__ deg,
    const int* __restrict__ colall,
    const float* __restrict__ rel_attn_l, const float* __restrict__ rel_attn_r,
    const float* __restrict__ rel_bias,   float* __restrict__ out)
{
    const int wv   = threadIdx.x >> 6;
    const int lane = threadIdx.x & 63;
    const int g    = lane >> 5;          // node slot within wave (0/1)
    const int j    = lane & 31;          // lane within half
    const int n    = blockIdx.x * 8 + wv * 2 + g;
    if (n >= N_NODES) return;

    const int h  = j >> 3;               // head 0..3 (8 lanes per head)
    const int c4 = j * 4;                // first of 4 owned channels
    const int gbase = lane & 32;         // shfl base for own half

    int   start_[3], cnt_[3], cm_[3], base_[3];
    float4 ar4_[3];
#pragma unroll
    for (int rr = 0; rr < 3; ++rr) {
        start_[rr] = rowst[rr * N_NODES + n];
        cnt_[rr]   = deg[rr * N_NODES + n];
        ar4_[rr]   = *reinterpret_cast<const float4*>(ar + (size_t)n * 12 + rr * 4);
        const int co = __shfl(cnt_[rr], lane ^ 32);
        cm_[rr] = max(cnt_[rr], co);
        base_[rr] = 0;
    }

    float ex[3][4];
    float den[3];
#pragma unroll
    for (int rr = 0; rr < 3; ++rr) {
        den[rr] = 0.f;
#pragma unroll
        for (int c = 0; c < 4; ++c) ex[rr][c] = 0.f;
    }

    while (base_[0] < cm_[0] || base_[1] < cm_[1] || base_[2] < cm_[2]) {
        int   mx_[3];
        int   sj_[3];
        float w_[3][4];
        // ---- phase A: per-relation per-lane edge weights (independent loads)
#pragma unroll
        for (int rr = 0; rr < 3; ++rr) {
            mx_[rr] = 0; sj_[rr] = 0;
            w_[rr][0] = 0.f; w_[rr][1] = 0.f; w_[rr][2] = 0.f; w_[rr][3] = 0.f;
            if (base_[rr] < cm_[rr]) {                       // wave-uniform
                const int mm = min(32, max(0, cnt_[rr] - base_[rr]));
                mx_[rr] = min(32, cm_[rr] - base_[rr]);
                sj_[rr] = (j < mm) ? colall[start_[rr] + base_[rr] + j] : 0;
                const float4 al4 = *reinterpret_cast<const float4*>(
                    al + (size_t)sj_[rr] * 12 + rr * 4);
                float t0 = al4.x + ar4_[rr].x, t1 = al4.y + ar4_[rr].y;
                float t2 = al4.z + ar4_[rr].z, t3 = al4.w + ar4_[rr].w;
                t0 = fmaxf(t0, 0.2f * t0); t1 = fmaxf(t1, 0.2f * t1);
                t2 = fmaxf(t2, 0.2f * t2); t3 = fmaxf(t3, 0.2f * t3);
                float e0 = __expf(t0), e1 = __expf(t1);
                float e2 = __expf(t2), e3 = __expf(t3);
                if (j >= mm) { e0 = 0.f; e1 = 0.f; e2 = 0.f; e3 = 0.f; }
                w_[rr][0] = e0; w_[rr][1] = e1; w_[rr][2] = e2; w_[rr][3] = e3;
            }
        }
        // ---- phase B: combined serial loop, 3 gathers in flight
        const int mxall = max(mx_[0], max(mx_[1], mx_[2]));
        for (int i = 0; i < mxall; ++i) {
#pragma unroll
            for (int rr = 0; rr < 3; ++rr) {
                if (i < mx_[rr]) {                           // wave-uniform
                    const int sl   = gbase + i;
                    const int srcI = __shfl(sj_[rr], sl);
                    const float b0 = __shfl(w_[rr][0], sl);
                    const float b1 = __shfl(w_[rr][1], sl);
                    const float b2 = __shfl(w_[rr][2], sl);
                    const float b3 = __shfl(w_[rr][3], sl);
                    const float wsel = (h & 2) ? ((h & 1) ? b3 : b2)
                                               : ((h & 1) ? b1 : b0);
                    const uint2 u = *reinterpret_cast<const uint2*>(
                        lbf32 + (size_t)srcI * 64 + j * 2);
                    den[rr] += wsel;
                    ex[rr][0] = fmaf(wsel, __uint_as_float(u.x << 16),         ex[rr][0]);
                    ex[rr][1] = fmaf(wsel, __uint_as_float(u.x & 0xFFFF0000u), ex[rr][1]);
                    ex[rr][2] = fmaf(wsel, __uint_as_float(u.y << 16),         ex[rr][2]);
                    ex[rr][3] = fmaf(wsel, __uint_as_float(u.y & 0xFFFF0000u), ex[rr][3]);
                }
            }
        }
#pragma unroll
        for (int rr = 0; rr < 3; ++rr) base_[rr] += 32;
    }

    // normalized relation embeddings + self slot (bf16)
    float e[4][4];
#pragma unroll
    for (int rr = 0; rr < 3; ++rr) {
        const float inv = 1.f / (den[rr] + 1e-16f);
#pragma unroll
        for (int c = 0; c < 4; ++c) e[rr][c] = ex[rr][c] * inv;
    }
    {
        const uint2 u = *reinterpret_cast<const uint2*>(lbf32 + (size_t)n * 64 + j * 2);
        e[3][0] = __uint_as_float(u.x << 16);
        e[3][1] = __uint_as_float(u.x & 0xFFFF0000u);
        e[3][2] = __uint_as_float(u.y << 16);
        e[3][3] = __uint_as_float(u.y & 0xFFFF0000u);
    }

    // relation-level beta attention
    const float4 rv4  = *reinterpret_cast<const float4*>(rbuf + (size_t)n * D_OUTF + c4);
    const float4 ral4 = *reinterpret_cast<const float4*>(rel_attn_l + c4);
    float blc[4];
    blc[0] = fmaxf(rv4.x * ral4.x, 0.f);
    blc[1] = fmaxf(rv4.y * ral4.y, 0.f);
    blc[2] = fmaxf(rv4.z * ral4.z, 0.f);
    blc[3] = fmaxf(rv4.w * ral4.w, 0.f);

    float beta[4];
#pragma unroll
    for (int s = 0; s < 4; ++s) {
        const float4 rar4 = *reinterpret_cast<const float4*>(rel_attn_r + s * D_OUTF + c4);
        float p = 0.f;
        p = fmaf(blc[0], fmaxf(e[s][0] * rar4.x, 0.f), p);
        p = fmaf(blc[1], fmaxf(e[s][1] * rar4.y, 0.f), p);
        p = fmaf(blc[2], fmaxf(e[s][2] * rar4.z, 0.f), p);
        p = fmaf(blc[3], fmaxf(e[s][3] * rar4.w, 0.f), p);
#pragma unroll
        for (int m = 4; m >= 1; m >>= 1) p += __shfl_xor(p, m);
        beta[s] = p + rel_bias[s];
    }

    // softmax over the 4 relation slots (per head)
    const float mx2 = fmaxf(fmaxf(beta[0], beta[1]), fmaxf(beta[2], beta[3]));
    float ssum = 0.f;
#pragma unroll
    for (int s = 0; s < 4; ++s) { beta[s] = __expf(beta[s] - mx2); ssum += beta[s]; }
    const float isum = 1.f / ssum;
    float4 ov;
    float o0 = 0.f, o1 = 0.f, o2 = 0.f, o3 = 0.f;
#pragma unroll
    for (int s = 0; s < 4; ++s) {
        const float b = beta[s] * isum;
        o0 = fmaf(e[s][0], b, o0);
        o1 = fmaf(e[s][1], b, o1);
        o2 = fmaf(e[s][2], b, o2);
        o3 = fmaf(e[s][3], b, o3);
    }
    ov.x = fmaxf(o0, 0.f);
    ov.y = fmaxf(o1, 0.f);
    ov.z = fmaxf(o2, 0.f);
    ov.w = fmaxf(o3, 0.f);
    *reinterpret_cast<float4*>(out + (size_t)n * D_OUTF + c4) = ov;
}

// ---------------------------------------------------------------------------
extern "C" void kernel_launch(void* const* d_in, const int* in_sizes, int n_in,
                              void* d_out, int out_size, void* d_ws, size_t ws_size,
                              hipStream_t stream)
{
    const float* x     = (const float*)d_in[0];
    const int*   ei    = (const int*)  d_in[1];
    const float* Wl    = (const float*)d_in[2];
    const float* bl    = (const float*)d_in[3];
    const float* Wr    = (const float*)d_in[4];
    const float* br    = (const float*)d_in[5];
    const float* attn  = (const float*)d_in[6];
    const float* ral   = (const float*)d_in[7];
    const float* rar   = (const float*)d_in[8];
    const float* rbias = (const float*)d_in[9];
    float* out = (float*)d_out;

    char* ws = (char*)d_ws;
    size_t off = 0;
    float* rbuf   = (float*)(ws + off); off += (size_t)N_NODES * D_OUTF * 4;   // 51.2 MB
    float* al     = (float*)(ws + off); off += (size_t)N_NODES * 12 * 4;       // 4.8 MB
    float* ar     = (float*)(ws + off); off += (size_t)N_NODES * 12 * 4;       // 4.8 MB
    int*   deg    = (int*)  (ws + off); off += (size_t)3 * N_NODES * 4;        // 1.2 MB
    int*   rowst  = (int*)  (ws + off); off += (size_t)3 * N_NODES * 4;        // 1.2 MB
    int*   cursor = (int*)  (ws + off); off += (size_t)3 * N_NODES * 4;        // 1.2 MB
    int*   colall = (int*)  (ws + off); off += (size_t)3 * N_EDGES * 4;        // 7.2 MB
    int*   blksum = (int*)  (ws + off); off += (size_t)512 * 4;
    unsigned short* wt  = (unsigned short*)(ws + off); off += (size_t)2 * 2 * 128 * 256 * 2; // 256 KB
    unsigned short* lbf = (unsigned short*)(ws + off); off += (size_t)N_NODES * D_OUTF * 2;  // 25.6 MB

    hipMemsetAsync(deg, 0, (size_t)3 * N_NODES * 4, stream);

    wt_prep<<<dim3(256, 2), 128, 0, stream>>>(Wl, Wr, wt);

    dim3 eg((N_EDGES + 255) / 256, 3);
    hist_kernel<<<eg, 256, 0, stream>>>(ei, deg);
    scan_reduce<<<SCAN_NBLK, 256, 0, stream>>>(deg, blksum);
    scan_mid<<<1, 512, 0, stream>>>(blksum);
    scan_final<<<SCAN_NBLK, 256, 0, stream>>>(deg, blksum, rowst, cursor);

    // fused: proj (compute-bound) overlapped with CSR scatter (latency-bound)
    proj_scatter<<<NTOT_BLOCKS, 256, 0, stream>>>(
        x, wt, bl, br, attn, rbuf, al, ar, lbf, ei, cursor, colall);

    aggregate_kernel<<<(N_NODES + 7) / 8, 256, 0, stream>>>(
        (const unsigned int*)lbf, rbuf, al, ar, rowst, deg, colall,
        ral, rar, rbias, out);
}

// Round 13
// 335.081 us; speedup vs baseline: 1.0620x; 1.0620x over previous
//
#include <hip/hip_runtime.h>
#include <hip/hip_bf16.h>

#define N_NODES 100000
#define N_EDGES 600000
#define N_REL   3
#define D_INF   256
#define D_OUTF  128

#define SCAN_TOTAL (3 * N_NODES)                 // 300000
#define SCAN_ELEMS 1024                          // elems per block
#define SCAN_NBLK  ((SCAN_TOTAL + SCAN_ELEMS - 1) / SCAN_ELEMS)  // 293

#define NPROJ_BLOCKS (((N_NODES + 63) / 64) * 2)        // 3126
#define NSCAT_BLOCKS ((3 * N_EDGES + 255) / 256)        // 7032
#define NTOT_BLOCKS  (NPROJ_BLOCKS + NSCAT_BLOCKS)      // 10158

typedef __attribute__((ext_vector_type(8))) short          bf16x8;
typedef __attribute__((ext_vector_type(8))) unsigned short ushort8;
typedef __attribute__((ext_vector_type(4))) float          f32x4;

// x-tile LDS row stride (bf16 elems): 144B rows, 16B aligned, ~2-way bank
#define LPAD 72
// phase-2 lbf staging stride (reuses xs region): 272B rows
#define LTS  136

__device__ __forceinline__ unsigned short bf16_rne(float v) {
    unsigned int b = __float_as_uint(v);
    b += 0x7FFFu + ((b >> 16) & 1u);
    return (unsigned short)(b >> 16);
}

// ---------------------------------------------------------------------------
// K0 (FUSED): wt_prep (blocks 0..255) + degree histogram (rest).
// wt packed in MFMA B-fragment order (see R11 comment).
// ---------------------------------------------------------------------------
__global__ __launch_bounds__(256) void prep_hist(
    const float* __restrict__ Wl, const float* __restrict__ Wr,
    unsigned short* __restrict__ wt,
    const int* __restrict__ ei, int* __restrict__ deg)
{
    const int bid = blockIdx.x;
    const int t   = threadIdx.x;
    if (bid < 256) {
        const int k = bid;
        const int w = t >> 7;
        const int n = t & 127;
        const float v = (w ? Wr : Wl)[(size_t)k * D_OUTF + n];
        const unsigned short h = bf16_rne(v);
        const float fhi = __uint_as_float(((unsigned int)h) << 16);
        const unsigned short g = bf16_rne(v - fhi);
        const int kb   = k >> 6;
        const int kk   = (k >> 5) & 1;
        const int lgrp = (k >> 3) & 3;
        const int j    = k & 7;
        const int cf   = n >> 4;
        const int lane = lgrp * 16 + (n & 15);
        const size_t fh = ((((size_t)(w * 2 + 0) * 4 + kb) * 2 + kk) * 8 + cf) * 512 + lane * 8 + j;
        const size_t fl = ((((size_t)(w * 2 + 1) * 4 + kb) * 2 + kk) * 8 + cf) * 512 + lane * 8 + j;
        wt[fh] = h;
        wt[fl] = g;
        return;
    }
    const int ge = (bid - 256) * 256 + t;
    if (ge < 3 * N_EDGES) {
        const int rr = (ge >= 2 * N_EDGES) ? 2 : ((ge >= N_EDGES) ? 1 : 0);
        const int e  = ge - rr * N_EDGES;
        const int dst = ei[(size_t)rr * 2 * N_EDGES + N_EDGES + e];
        atomicAdd(&deg[rr * N_NODES + dst], 1);
    }
}

// ---------------------------------------------------------------------------
// K1 (FUSED): proj GEMM (split-bf16 MFMA; W from packed global frags; al/ar
// via in-register f32 dot + shfl reduce) ∥ CSR scatter.
// al written in PER-RELATION layout alr[3][N][4] (L2-fit gather table).
// ---------------------------------------------------------------------------
__global__ __launch_bounds__(256, 4) void proj_scatter(
    const float* __restrict__ x, const unsigned short* __restrict__ wt,
    const float* __restrict__ bl, const float* __restrict__ br,
    const float* __restrict__ attn,
    float* __restrict__ rbuf,
    float* __restrict__ alr,  float* __restrict__ ar,
    unsigned short* __restrict__ lbf,
    const int* __restrict__ ei, int* __restrict__ cursor,
    int* __restrict__ colall)
{
    __shared__ unsigned short smem[2 * 64 * LPAD];   // 18432 B

    const int bid = blockIdx.x;
    const unsigned int pb = (unsigned int)(((unsigned long long)bid * NPROJ_BLOCKS) / NTOT_BLOCKS);
    const unsigned int pa = (unsigned int)(((unsigned long long)(bid + 1) * NPROJ_BLOCKS) / NTOT_BLOCKS);

    if (pa == pb) {
        // ================= scatter block =================
        const int sb = bid - (int)pb;
        const int ge = sb * 256 + threadIdx.x;
        if (ge < 3 * N_EDGES) {
            const int rr = (ge >= 2 * N_EDGES) ? 2 : ((ge >= N_EDGES) ? 1 : 0);
            const int e  = ge - rr * N_EDGES;
            const int src = ei[(size_t)rr * 2 * N_EDGES + e];
            const int dst = ei[(size_t)rr * 2 * N_EDGES + N_EDGES + e];
            const int pos = atomicAdd(&cursor[rr * N_NODES + dst], 1);
            colall[pos] = src;
        }
        return;
    }

    // ================= proj block #pb =================
    const int tid  = threadIdx.x;
    const int nb   = (int)(pb >> 1) * 64;
    const int w    = (int)(pb & 1);
    const float* bias = w ? br : bl;

    const int lane = tid & 63;
    const int wv   = tid >> 6;      // wave 0..3
    const int rowf = lane & 15;
    const int kgrp = lane >> 4;     // 0..3

    f32x4 acc[8];
#pragma unroll
    for (int cf = 0; cf < 8; ++cf) acc[cf] = (f32x4){0.f, 0.f, 0.f, 0.f};

    float bv[8];
#pragma unroll
    for (int cf = 0; cf < 8; ++cf) bv[cf] = bias[cf * 16 + rowf];

    for (int kb4 = 0; kb4 < 4; ++kb4) {
        __syncthreads();
        // ---- stage x tile: thread t -> row t>>2, 16 k's at (t&3)*16
        {
            const int r   = tid >> 2;
            const int seg = tid & 3;
            int rowg = nb + r; if (rowg >= N_NODES) rowg = N_NODES - 1;
            const float* src = x + (size_t)rowg * D_INF + kb4 * 64 + seg * 16;
#pragma unroll
            for (int q2 = 0; q2 < 2; ++q2) {
                const float4 v0 = *reinterpret_cast<const float4*>(src + q2 * 8);
                const float4 v1 = *reinterpret_cast<const float4*>(src + q2 * 8 + 4);
                const float vv[8] = {v0.x, v0.y, v0.z, v0.w, v1.x, v1.y, v1.z, v1.w};
                ushort8 hv, gv;
#pragma unroll
                for (int q = 0; q < 8; ++q) {
                    const unsigned short h = bf16_rne(vv[q]);
                    hv[q] = h;
                    const float fhi = __uint_as_float(((unsigned int)h) << 16);
                    gv[q] = bf16_rne(vv[q] - fhi);
                }
                *reinterpret_cast<ushort8*>(&smem[0 * 64 * LPAD + r * LPAD + seg * 16 + q2 * 8]) = hv;
                *reinterpret_cast<ushort8*>(&smem[1 * 64 * LPAD + r * LPAD + seg * 16 + q2 * 8]) = gv;
            }
        }
        __syncthreads();

        // ---- MFMA; B-frags loaded directly from packed wt (coalesced, L1/L2)
#pragma unroll
        for (int kk = 0; kk < 2; ++kk) {
            const int ko = kk * 32 + kgrp * 8;
            const bf16x8 ahi = *reinterpret_cast<const bf16x8*>(&smem[0 * 64 * LPAD + (wv * 16 + rowf) * LPAD + ko]);
            const bf16x8 alo = *reinterpret_cast<const bf16x8*>(&smem[1 * 64 * LPAD + (wv * 16 + rowf) * LPAD + ko]);
#pragma unroll
            for (int cf = 0; cf < 8; ++cf) {
                const bf16x8 bhi = *reinterpret_cast<const bf16x8*>(
                    wt + ((((size_t)(w * 2 + 0) * 4 + kb4) * 2 + kk) * 8 + cf) * 512 + lane * 8);
                const bf16x8 blo = *reinterpret_cast<const bf16x8*>(
                    wt + ((((size_t)(w * 2 + 1) * 4 + kb4) * 2 + kk) * 8 + cf) * 512 + lane * 8);
                acc[cf] = __builtin_amdgcn_mfma_f32_16x16x32_bf16(ahi, bhi, acc[cf], 0, 0, 0);
                acc[cf] = __builtin_amdgcn_mfma_f32_16x16x32_bf16(ahi, blo, acc[cf], 0, 0, 0);
                acc[cf] = __builtin_amdgcn_mfma_f32_16x16x32_bf16(alo, bhi, acc[cf], 0, 0, 0);
            }
        }
    }
    __syncthreads();   // xs reads done; safe to reuse smem in phase 2

    // ==== phase 2: relu + outputs ====
    float o_[8][4];
#pragma unroll
    for (int cf = 0; cf < 8; ++cf)
#pragma unroll
        for (int j = 0; j < 4; ++j)
            o_[cf][j] = fmaxf(acc[cf][j] + bv[cf], 0.f);

    if (w == 1) {
#pragma unroll
        for (int cf = 0; cf < 8; ++cf)
#pragma unroll
            for (int j = 0; j < 4; ++j) {
                const int node = nb + wv * 16 + kgrp * 4 + j;
                if (node < N_NODES)
                    rbuf[(size_t)node * D_OUTF + cf * 16 + rowf] = o_[cf][j];
            }
    }

    // al/ar: f32 dot with attn band + 16-lane shfl reduce (over rowf)
    {
        const int woff = w ? 32 : 0;
#pragma unroll
        for (int rr = 0; rr < 3; ++rr) {
            float pr[4][4];
#pragma unroll
            for (int hh = 0; hh < 4; ++hh) {
                const float A0 = attn[rr * 256 + hh * 64 + woff + rowf];
                const float A1 = attn[rr * 256 + hh * 64 + woff + 16 + rowf];
#pragma unroll
                for (int j = 0; j < 4; ++j)
                    pr[hh][j] = fmaf(o_[2 * hh][j], A0, o_[2 * hh + 1][j] * A1);
            }
#pragma unroll
            for (int hh = 0; hh < 4; ++hh)
#pragma unroll
                for (int j = 0; j < 4; ++j) {
#pragma unroll
                    for (int m = 8; m >= 1; m >>= 1)
                        pr[hh][j] += __shfl_xor(pr[hh][j], m);
                }
            if ((rowf >> 2) == rr) {
#pragma unroll
                for (int j = 0; j < 4; ++j) {
                    float v = pr[0][j];
#pragma unroll
                    for (int hh = 1; hh < 4; ++hh)
                        if ((rowf & 3) == hh) v = pr[hh][j];
                    const int node = nb + wv * 16 + kgrp * 4 + j;
                    if (node < N_NODES) {
                        if (w == 0)
                            alr[((size_t)rr * N_NODES + node) * 4 + (rowf & 3)] = v;
                        else
                            ar[(size_t)node * 12 + rowf] = v;
                    }
                }
            }
        }
    }

    // lbf (bf16 l copy) via smem staging, coalesced  (w==0 only)
    if (w == 0) {
#pragma unroll
        for (int cf = 0; cf < 8; ++cf)
#pragma unroll
            for (int j = 0; j < 4; ++j)
                smem[(wv * 16 + kgrp * 4 + j) * LTS + cf * 16 + rowf] = bf16_rne(o_[cf][j]);
        __syncthreads();
#pragma unroll
        for (int q = 0; q < 4; ++q) {
            const int idx = tid + q * 256;     // 0..1023 chunks of 8 us
            const int r   = idx >> 4;
            const int c8  = (idx & 15) * 8;
            const int node = nb + r;
            if (node < N_NODES)
                *reinterpret_cast<ushort8*>(&lbf[(size_t)node * D_OUTF + c8]) =
                    *reinterpret_cast<ushort8*>(&smem[r * LTS + c8]);
        }
    }
}

// ---------------------------------------------------------------------------
// K4a: per-block reduce (1024 elems/block, 256 thr x 4)
// ---------------------------------------------------------------------------
__global__ __launch_bounds__(256) void scan_reduce(const int* __restrict__ deg,
                                                   int* __restrict__ blksum)
{
    __shared__ int ws[4];
    const int tid  = threadIdx.x;
    const int lane = tid & 63;
    const int wid  = tid >> 6;
    const int idx  = blockIdx.x * SCAN_ELEMS + tid * 4;
    int t = 0;
#pragma unroll
    for (int j = 0; j < 4; ++j)
        if (idx + j < SCAN_TOTAL) t += deg[idx + j];
#pragma unroll
    for (int off = 32; off >= 1; off >>= 1) t += __shfl_xor(t, off);
    if (lane == 0) ws[wid] = t;
    __syncthreads();
    if (tid == 0) blksum[blockIdx.x] = ws[0] + ws[1] + ws[2] + ws[3];
}

// ---------------------------------------------------------------------------
// K4b: single-block exclusive scan of the 293 block sums (512 threads)
// ---------------------------------------------------------------------------
__global__ __launch_bounds__(512) void scan_mid(int* __restrict__ blksum)
{
    __shared__ int sh[512];
    const int tid = threadIdx.x;
    const int v = (tid < SCAN_NBLK) ? blksum[tid] : 0;
    sh[tid] = v;
    __syncthreads();
#pragma unroll
    for (int off = 1; off < 512; off <<= 1) {
        const int u = (tid >= off) ? sh[tid - off] : 0;
        __syncthreads();
        sh[tid] += u;
        __syncthreads();
    }
    if (tid < SCAN_NBLK) blksum[tid] = sh[tid] - v;   // exclusive
}

// ---------------------------------------------------------------------------
// K4c: per-block scan + block offset -> rowst, cursor
// ---------------------------------------------------------------------------
__global__ __launch_bounds__(256) void scan_final(const int* __restrict__ deg,
    const int* __restrict__ blkoff, int* __restrict__ rowst,
    int* __restrict__ cursor)
{
    __shared__ int wsum[4];
    __shared__ int wexcl[4];
    const int tid  = threadIdx.x;
    const int lane = tid & 63;
    const int wid  = tid >> 6;
    const int idx  = blockIdx.x * SCAN_ELEMS + tid * 4;

    const int v0 = (idx + 0 < SCAN_TOTAL) ? deg[idx + 0] : 0;
    const int v1 = (idx + 1 < SCAN_TOTAL) ? deg[idx + 1] : 0;
    const int v2 = (idx + 2 < SCAN_TOTAL) ? deg[idx + 2] : 0;
    const int v3 = (idx + 3 < SCAN_TOTAL) ? deg[idx + 3] : 0;
    const int tsum = v0 + v1 + v2 + v3;
    int inc = tsum;
#pragma unroll
    for (int off = 1; off < 64; off <<= 1) {
        const int u = __shfl_up(inc, off);
        if (lane >= off) inc += u;
    }
    if (lane == 63) wsum[wid] = inc;
    __syncthreads();
    if (tid == 0) {
        int s = 0;
#pragma unroll
        for (int i = 0; i < 4; ++i) { const int t2 = wsum[i]; wexcl[i] = s; s += t2; }
    }
    __syncthreads();
    const int start = blkoff[blockIdx.x] + wexcl[wid] + (inc - tsum);
    if (idx + 0 < SCAN_TOTAL) { rowst[idx + 0] = start; cursor[idx + 0] = start; }
    const int s1 = start + v0;
    if (idx + 1 < SCAN_TOTAL) { rowst[idx + 1] = s1; cursor[idx + 1] = s1; }
    const int s2 = s1 + v1;
    if (idx + 2 < SCAN_TOTAL) { rowst[idx + 2] = s2; cursor[idx + 2] = s2; }
    const int s3 = s2 + v2;
    if (idx + 3 < SCAN_TOTAL) { rowst[idx + 3] = s3; cursor[idx + 3] = s3; }
}

// ---------------------------------------------------------------------------
// K6: aggregation v5.  2 nodes per wave (32 lanes each, 4 ch/lane); fused
// relations; phase A -> LDS (src + 4 weights per edge), phase B: 2 ds_reads
// per edge (src broadcast, wsel bank-parallel) + coalesced uint2 gather.
// al gathered from per-relation table alr[3][N][4] (1.6 MB, L2-resident).
// ---------------------------------------------------------------------------
__global__ __launch_bounds__(256) void aggregate_kernel(
    const unsigned int* __restrict__ lbf32, const float* __restrict__ rbuf,
    const float* __restrict__ alr,  const float* __restrict__ ar,
    const int* __restrict__ rowst,  const int* __restrict__ deg,
    const int* __restrict__ colall,
    const float* __restrict__ rel_attn_l, const float* __restrict__ rel_attn_r,
    const float* __restrict__ rel_bias,   float* __restrict__ out)
{
    __shared__ int   src_sh[4][2][3][32];        // 3 KB
    __shared__ float w_sh[4][2][3][32][4];       // 12 KB

    const int wv   = threadIdx.x >> 6;
    const int lane = threadIdx.x & 63;
    const int g    = lane >> 5;          // node slot within wave (0/1)
    const int j    = lane & 31;          // lane within half
    const int n    = blockIdx.x * 8 + wv * 2 + g;
    if (n >= N_NODES) return;

    const int h  = j >> 3;               // head 0..3 (8 lanes per head)
    const int c4 = j * 4;                // first of 4 owned channels

    int   start_[3], cnt_[3], cm_[3], base_[3];
    float4 ar4_[3];
#pragma unroll
    for (int rr = 0; rr < 3; ++rr) {
        start_[rr] = rowst[rr * N_NODES + n];
        cnt_[rr]   = deg[rr * N_NODES + n];
        ar4_[rr]   = *reinterpret_cast<const float4*>(ar + (size_t)n * 12 + rr * 4);
        const int co = __shfl(cnt_[rr], lane ^ 32);
        cm_[rr] = max(cnt_[rr], co);
        base_[rr] = 0;
    }

    float ex[3][4];
    float den[3];
#pragma unroll
    for (int rr = 0; rr < 3; ++rr) {
        den[rr] = 0.f;
#pragma unroll
        for (int c = 0; c < 4; ++c) ex[rr][c] = 0.f;
    }

    while (base_[0] < cm_[0] || base_[1] < cm_[1] || base_[2] < cm_[2]) {
        int mx_[3];
        // ---- phase A: per-relation per-lane edge weights -> LDS
#pragma unroll
        for (int rr = 0; rr < 3; ++rr) {
            mx_[rr] = 0;
            if (base_[rr] < cm_[rr]) {                       // wave-uniform
                const int mm = min(32, max(0, cnt_[rr] - base_[rr]));
                mx_[rr] = min(32, cm_[rr] - base_[rr]);
                const int sj = (j < mm) ? colall[start_[rr] + base_[rr] + j] : 0;
                const float4 al4 = *reinterpret_cast<const float4*>(
                    alr + ((size_t)rr * N_NODES + sj) * 4);
                float t0 = al4.x + ar4_[rr].x, t1 = al4.y + ar4_[rr].y;
                float t2 = al4.z + ar4_[rr].z, t3 = al4.w + ar4_[rr].w;
                t0 = fmaxf(t0, 0.2f * t0); t1 = fmaxf(t1, 0.2f * t1);
                t2 = fmaxf(t2, 0.2f * t2); t3 = fmaxf(t3, 0.2f * t3);
                float e0 = __expf(t0), e1 = __expf(t1);
                float e2 = __expf(t2), e3 = __expf(t3);
                if (j >= mm) { e0 = 0.f; e1 = 0.f; e2 = 0.f; e3 = 0.f; }
                src_sh[wv][g][rr][j] = sj;
                f32x4 w4; w4[0] = e0; w4[1] = e1; w4[2] = e2; w4[3] = e3;
                *reinterpret_cast<f32x4*>(&w_sh[wv][g][rr][j][0]) = w4;
            }
        }
        // ---- phase B: combined serial loop, 3 gathers in flight
        const int mxall = max(mx_[0], max(mx_[1], mx_[2]));
        for (int i = 0; i < mxall; ++i) {
#pragma unroll
            for (int rr = 0; rr < 3; ++rr) {
                if (i < mx_[rr]) {                           // wave-uniform
                    const int   srcI = src_sh[wv][g][rr][i];
                    const float wsel = w_sh[wv][g][rr][i][h];
                    const uint2 u = *reinterpret_cast<const uint2*>(
                        lbf32 + (size_t)srcI * 64 + j * 2);
                    den[rr] += wsel;
                    ex[rr][0] = fmaf(wsel, __uint_as_float(u.x << 16),         ex[rr][0]);
                    ex[rr][1] = fmaf(wsel, __uint_as_float(u.x & 0xFFFF0000u), ex[rr][1]);
                    ex[rr][2] = fmaf(wsel, __uint_as_float(u.y << 16),         ex[rr][2]);
                    ex[rr][3] = fmaf(wsel, __uint_as_float(u.y & 0xFFFF0000u), ex[rr][3]);
                }
            }
        }
#pragma unroll
        for (int rr = 0; rr < 3; ++rr) base_[rr] += 32;
    }

    // normalized relation embeddings + self slot (bf16)
    float e[4][4];
#pragma unroll
    for (int rr = 0; rr < 3; ++rr) {
        const float inv = 1.f / (den[rr] + 1e-16f);
#pragma unroll
        for (int c = 0; c < 4; ++c) e[rr][c] = ex[rr][c] * inv;
    }
    {
        const uint2 u = *reinterpret_cast<const uint2*>(lbf32 + (size_t)n * 64 + j * 2);
        e[3][0] = __uint_as_float(u.x << 16);
        e[3][1] = __uint_as_float(u.x & 0xFFFF0000u);
        e[3][2] = __uint_as_float(u.y << 16);
        e[3][3] = __uint_as_float(u.y & 0xFFFF0000u);
    }

    // relation-level beta attention
    const float4 rv4  = *reinterpret_cast<const float4*>(rbuf + (size_t)n * D_OUTF + c4);
    const float4 ral4 = *reinterpret_cast<const float4*>(rel_attn_l + c4);
    float blc[4];
    blc[0] = fmaxf(rv4.x * ral4.x, 0.f);
    blc[1] = fmaxf(rv4.y * ral4.y, 0.f);
    blc[2] = fmaxf(rv4.z * ral4.z, 0.f);
    blc[3] = fmaxf(rv4.w * ral4.w, 0.f);

    float beta[4];
#pragma unroll
    for (int s = 0; s < 4; ++s) {
        const float4 rar4 = *reinterpret_cast<const float4*>(rel_attn_r + s * D_OUTF + c4);
        float p = 0.f;
        p = fmaf(blc[0], fmaxf(e[s][0] * rar4.x, 0.f), p);
        p = fmaf(blc[1], fmaxf(e[s][1] * rar4.y, 0.f), p);
        p = fmaf(blc[2], fmaxf(e[s][2] * rar4.z, 0.f), p);
        p = fmaf(blc[3], fmaxf(e[s][3] * rar4.w, 0.f), p);
#pragma unroll
        for (int m = 4; m >= 1; m >>= 1) p += __shfl_xor(p, m);
        beta[s] = p + rel_bias[s];
    }

    // softmax over the 4 relation slots (per head)
    const float mx2 = fmaxf(fmaxf(beta[0], beta[1]), fmaxf(beta[2], beta[3]));
    float ssum = 0.f;
#pragma unroll
    for (int s = 0; s < 4; ++s) { beta[s] = __expf(beta[s] - mx2); ssum += beta[s]; }
    const float isum = 1.f / ssum;
    float4 ov;
    float o0 = 0.f, o1 = 0.f, o2 = 0.f, o3 = 0.f;
#pragma unroll
    for (int s = 0; s < 4; ++s) {
        const float b = beta[s] * isum;
        o0 = fmaf(e[s][0], b, o0);
        o1 = fmaf(e[s][1], b, o1);
        o2 = fmaf(e[s][2], b, o2);
        o3 = fmaf(e[s][3], b, o3);
    }
    ov.x = fmaxf(o0, 0.f);
    ov.y = fmaxf(o1, 0.f);
    ov.z = fmaxf(o2, 0.f);
    ov.w = fmaxf(o3, 0.f);
    *reinterpret_cast<float4*>(out + (size_t)n * D_OUTF + c4) = ov;
}

// ---------------------------------------------------------------------------
extern "C" void kernel_launch(void* const* d_in, const int* in_sizes, int n_in,
                              void* d_out, int out_size, void* d_ws, size_t ws_size,
                              hipStream_t stream)
{
    const float* x     = (const float*)d_in[0];
    const int*   ei    = (const int*)  d_in[1];
    const float* Wl    = (const float*)d_in[2];
    const float* bl    = (const float*)d_in[3];
    const float* Wr    = (const float*)d_in[4];
    const float* br    = (const float*)d_in[5];
    const float* attn  = (const float*)d_in[6];
    const float* ral   = (const float*)d_in[7];
    const float* rar   = (const float*)d_in[8];
    const float* rbias = (const float*)d_in[9];
    float* out = (float*)d_out;

    char* ws = (char*)d_ws;
    size_t off = 0;
    float* rbuf   = (float*)(ws + off); off += (size_t)N_NODES * D_OUTF * 4;   // 51.2 MB
    float* alr    = (float*)(ws + off); off += (size_t)3 * N_NODES * 4 * 4;    // 4.8 MB
    float* ar     = (float*)(ws + off); off += (size_t)N_NODES * 12 * 4;       // 4.8 MB
    int*   deg    = (int*)  (ws + off); off += (size_t)3 * N_NODES * 4;        // 1.2 MB
    int*   rowst  = (int*)  (ws + off); off += (size_t)3 * N_NODES * 4;        // 1.2 MB
    int*   cursor = (int*)  (ws + off); off += (size_t)3 * N_NODES * 4;        // 1.2 MB
    int*   colall = (int*)  (ws + off); off += (size_t)3 * N_EDGES * 4;        // 7.2 MB
    int*   blksum = (int*)  (ws + off); off += (size_t)512 * 4;
    unsigned short* wt  = (unsigned short*)(ws + off); off += (size_t)2 * 2 * 128 * 256 * 2; // 256 KB
    unsigned short* lbf = (unsigned short*)(ws + off); off += (size_t)N_NODES * D_OUTF * 2;  // 25.6 MB

    hipMemsetAsync(deg, 0, (size_t)3 * N_NODES * 4, stream);

    prep_hist<<<256 + NSCAT_BLOCKS, 256, 0, stream>>>(Wl, Wr, wt, ei, deg);
    scan_reduce<<<SCAN_NBLK, 256, 0, stream>>>(deg, blksum);
    scan_mid<<<1, 512, 0, stream>>>(blksum);
    scan_final<<<SCAN_NBLK, 256, 0, stream>>>(deg, blksum, rowst, cursor);

    // fused: proj (compute-bound) overlapped with CSR scatter (latency-bound)
    proj_scatter<<<NTOT_BLOCKS, 256, 0, stream>>>(
        x, wt, bl, br, attn, rbuf, alr, ar, lbf, ei, cursor, colall);

    aggregate_kernel<<<(N_NODES + 7) / 8, 256, 0, stream>>>(
        (const unsigned int*)lbf, rbuf, alr, ar, rowst, deg, colall,
        ral, rar, rbias, out);
}